// Round 1
// baseline (901.941 us; speedup 1.0000x reference)
//
#include <hip/hip_runtime.h>
#include <math.h>

#define NUSERS 40000
#define NENT   80000
#define NITEMS 30000
#define DIM    64
#define EKG    800000
#define EUI    600000

// ---------- helpers ----------
static __device__ __forceinline__ float grp16_sum(float v) {
    v += __shfl_xor(v, 1);
    v += __shfl_xor(v, 2);
    v += __shfl_xor(v, 4);
    v += __shfl_xor(v, 8);
    return v;
}

// ---------- CSR build ----------
__global__ void count_kernel(const int* __restrict__ ehead,
                             const int* __restrict__ iuser,
                             const int* __restrict__ iitem,
                             int* __restrict__ cnth, int* __restrict__ cntu,
                             int* __restrict__ cnti) {
    int e = blockIdx.x * blockDim.x + threadIdx.x;
    if (e < EKG) atomicAdd(&cnth[ehead[e]], 1);
    if (e < EUI) {
        atomicAdd(&cntu[iuser[e]], 1);
        atomicAdd(&cnti[iitem[e]], 1);
    }
}

// single-block exclusive scan; cnt[i] is replaced by its exclusive prefix
// (so it doubles as the fill cursor), off[i]=excl, off[n]=total.
__global__ void scan_excl_kernel(int* __restrict__ cnt, int* __restrict__ off, int n) {
    const int T = 256, IPT = 16, CH = T * IPT;
    __shared__ int wsum[4];
    __shared__ int s_carry;
    int tid = threadIdx.x, lane = tid & 63, wid = tid >> 6;
    if (tid == 0) s_carry = 0;
    __syncthreads();
    for (int base = 0; base < n; base += CH) {
        int vals[IPT];
        int i0 = base + tid * IPT;
        int tsum = 0;
#pragma unroll
        for (int k = 0; k < IPT; k++) {
            int i = i0 + k;
            int v = (i < n) ? cnt[i] : 0;
            vals[k] = tsum;  // exclusive within thread
            tsum += v;
        }
        int x = tsum;
#pragma unroll
        for (int d = 1; d < 64; d <<= 1) {
            int t = __shfl_up(x, d);
            if (lane >= d) x += t;
        }
        if (lane == 63) wsum[wid] = x;
        __syncthreads();
        int wbase = 0;
        for (int w = 0; w < wid; w++) wbase += wsum[w];
        int carry = s_carry;
        int tbase = carry + wbase + (x - tsum);
#pragma unroll
        for (int k = 0; k < IPT; k++) {
            int i = i0 + k;
            if (i < n) {
                int e = tbase + vals[k];
                off[i] = e;
                cnt[i] = e;
            }
        }
        __syncthreads();
        if (tid == T - 1) s_carry = carry + wbase + x;
        __syncthreads();
    }
    if (threadIdx.x == 0) off[n] = s_carry;
}

__global__ void fill_kernel(const int* __restrict__ ehead, const int* __restrict__ etail,
                            const int* __restrict__ etype,
                            const int* __restrict__ iuser, const int* __restrict__ iitem,
                            const float* __restrict__ iwin,
                            int* __restrict__ curh, int* __restrict__ curu, int* __restrict__ curi,
                            int* __restrict__ heid, int* __restrict__ hhead,
                            int* __restrict__ htail, int* __restrict__ htype,
                            int* __restrict__ uitem, float* __restrict__ uw,
                            int* __restrict__ iuserc, float* __restrict__ iw2) {
    int e = blockIdx.x * blockDim.x + threadIdx.x;
    if (e < EKG) {
        int h = ehead[e];
        int p = atomicAdd(&curh[h], 1);
        heid[p] = e;
        hhead[p] = h;
        htail[p] = etail[e];
        htype[p] = etype[e] - 1;
    }
    if (e < EUI) {
        int u = iuser[e], it = iitem[e];
        float w = iwin[e];
        int p = atomicAdd(&curu[u], 1);
        uitem[p] = it;
        uw[p] = w;
        int q = atomicAdd(&curi[it], 1);
        iuserc[q] = u;
        iw2[q] = w;
    }
}

// ---------- P = X @ W_Q ----------
__global__ void gemm_wq_kernel(const float* __restrict__ X, const float* __restrict__ W,
                               float* __restrict__ P) {
    __shared__ float Wl[64 * 64];
    int tid = threadIdx.x;
    for (int i = tid; i < 64 * 64; i += 256) Wl[i] = W[i];
    __syncthreads();
    int rloc = tid >> 4;          // 0..15
    int c4 = (tid & 15) * 4;      // col base
    int row = blockIdx.x * 16 + rloc;
    const float* x = X + (size_t)row * DIM;
    float ax = 0, ay = 0, az = 0, aw = 0;
#pragma unroll 8
    for (int d = 0; d < 64; d++) {
        float xv = x[d];
        const float4 w = *(const float4*)&Wl[d * 64 + c4];
        ax += xv * w.x;
        ay += xv * w.y;
        az += xv * w.z;
        aw += xv * w.w;
    }
    float4 o = {ax, ay, az, aw};
    *(float4*)&P[(size_t)row * DIM + c4] = o;
}

// ---------- per-edge attention (CSR order). att[j][h]; logit optional ----------
__global__ void attn_kernel(const float* __restrict__ P, const float* __restrict__ rel,
                            const int* __restrict__ hhead, const int* __restrict__ htail,
                            const int* __restrict__ htype,
                            float* __restrict__ att, float* __restrict__ logit) {
    int tid = threadIdx.x;
    int g = (blockIdx.x * blockDim.x + tid) >> 4;  // CSR index j
    if (g >= EKG) return;
    int l = tid & 15;
    int head = hhead[g], tail = htail[g], r = htype[g];
    const float4 q = *(const float4*)(P + (size_t)head * DIM + l * 4);
    const float4 k = *(const float4*)(P + (size_t)tail * DIM + l * 4);
    const float4 rv = *(const float4*)(rel + r * DIM + l * 4);
    float part = q.x * k.x * rv.x + q.y * k.y * rv.y + q.z * k.z * rv.z + q.w * k.w * rv.w;
    part += __shfl_xor(part, 1);
    part += __shfl_xor(part, 2);
    part += __shfl_xor(part, 4);
    float other = __shfl_xor(part, 8);
    const float sc = 0.17677669529663687f;  // 1/sqrt(32)
    if (l == 0) {
        att[2 * g] = part * sc;
        if (logit) logit[g] = (part + other) * sc * 0.5f;
    }
    if (l == 8) att[2 * g + 1] = part * sc;
}

// ---------- Part A: softmax(logits) by head -> edge_attn_score; item_attn_sumed ----------
__global__ void parta_kernel(const float* __restrict__ logit, const int* __restrict__ hoff,
                             const int* __restrict__ heid, const int* __restrict__ htail,
                             float* __restrict__ edge_score, float* __restrict__ item_sum) {
    int v = blockIdx.x * blockDim.x + threadIdx.x;
    if (v >= NENT) return;
    int o0 = hoff[v], o1 = hoff[v + 1];
    if (o0 != o1) {
        float m = -INFINITY;
        for (int j = o0; j < o1; j++) m = fmaxf(m, logit[j]);
        float s = 0.f, lsum = 0.f;
        for (int j = o0; j < o1; j++) {
            float l = logit[j];
            s += __expf(l - m);
            lsum += l;
        }
        float scale = (float)(o1 - o0) / (s + 1e-16f);
        for (int j = o0; j < o1; j++) {
            float l = logit[j];
            edge_score[heid[j]] = __expf(l - m) * scale;
            int t = htail[j];
            if (t < NITEMS) atomicAdd(&item_sum[t], l);
        }
        if (v < NITEMS) atomicAdd(&item_sum[v], lsum);
    }
}

// ---------- per-head segment softmax over head groups, in place ----------
__global__ void hsm_kernel(float* __restrict__ att, const int* __restrict__ hoff) {
    int v = blockIdx.x * blockDim.x + threadIdx.x;
    if (v >= NENT) return;
    int o0 = hoff[v], o1 = hoff[v + 1];
    if (o0 == o1) return;
#pragma unroll
    for (int h = 0; h < 2; h++) {
        float m = -INFINITY;
        for (int j = o0; j < o1; j++) m = fmaxf(m, att[2 * j + h]);
        float s = 0.f;
        for (int j = o0; j < o1; j++) s += __expf(att[2 * j + h] - m);
        float inv = 1.0f / (s + 1e-16f);
        for (int j = o0; j < o1; j++) att[2 * j + h] = __expf(att[2 * j + h] - m) * inv;
    }
}

// ---------- entity aggregation: KG + UI(user->item), l2norm, residual ----------
__global__ void agge_kernel(const float* __restrict__ ecur, const float* __restrict__ ucur,
                            const float* __restrict__ rel, const float* __restrict__ att,
                            const int* __restrict__ hoff, const int* __restrict__ htail,
                            const int* __restrict__ htype,
                            const int* __restrict__ ioff, const int* __restrict__ iuserc,
                            const float* __restrict__ iw2,
                            const float* __restrict__ resin, float* __restrict__ resout,
                            float* __restrict__ enxt) {
    int tid = threadIdx.x;
    int v = (blockIdx.x * blockDim.x + tid) >> 4;
    if (v >= NENT) return;
    int l = tid & 15;
    int h = l >> 3;
    float ax = 0, ay = 0, az = 0, aw = 0;
    int o0 = hoff[v], o1 = hoff[v + 1];
    for (int j = o0; j < o1; j++) {
        int t = htail[j];
        int r = htype[j];
        float s = att[2 * j + h];
        const float4 ev = *(const float4*)(ecur + (size_t)t * DIM + l * 4);
        const float4 rv = *(const float4*)(rel + r * DIM + l * 4);
        ax += ev.x * rv.x * s;
        ay += ev.y * rv.y * s;
        az += ev.z * rv.z * s;
        aw += ev.w * rv.w * s;
    }
    int p0 = ioff[v], p1 = ioff[v + 1];
    for (int j = p0; j < p1; j++) {
        int u = iuserc[j];
        float w = iw2[j];
        const float4 uv = *(const float4*)(ucur + (size_t)u * DIM + l * 4);
        ax += w * uv.x;
        ay += w * uv.y;
        az += w * uv.z;
        aw += w * uv.w;
    }
    float nsq = grp16_sum(ax * ax + ay * ay + az * az + aw * aw);
    float invn = 1.0f / fmaxf(sqrtf(nsq), 1e-12f);
    float ox = ax * invn, oy = ay * invn, oz = az * invn, ow = aw * invn;
    size_t base = (size_t)v * DIM + l * 4;
    if (enxt) {
        float4 o = {ox, oy, oz, ow};
        *(float4*)(enxt + base) = o;
    }
    const float4 ri = *(const float4*)(resin + base);
    float4 ro = {ri.x + ox, ri.y + oy, ri.z + oz, ri.w + ow};
    *(float4*)(resout + base) = ro;
}

// ---------- user aggregation: UI(item->user), l2norm, residual ----------
__global__ void aggu_kernel(const float* __restrict__ ecur,
                            const int* __restrict__ uoff, const int* __restrict__ uitem,
                            const float* __restrict__ uw,
                            const float* __restrict__ resin, float* __restrict__ resout,
                            float* __restrict__ unxt) {
    int tid = threadIdx.x;
    int v = (blockIdx.x * blockDim.x + tid) >> 4;
    if (v >= NUSERS) return;
    int l = tid & 15;
    float ax = 0, ay = 0, az = 0, aw = 0;
    int o0 = uoff[v], o1 = uoff[v + 1];
    for (int j = o0; j < o1; j++) {
        int it = uitem[j];
        float w = uw[j];
        const float4 ev = *(const float4*)(ecur + (size_t)it * DIM + l * 4);
        ax += w * ev.x;
        ay += w * ev.y;
        az += w * ev.z;
        aw += w * ev.w;
    }
    float nsq = grp16_sum(ax * ax + ay * ay + az * az + aw * aw);
    float invn = 1.0f / fmaxf(sqrtf(nsq), 1e-12f);
    float ox = ax * invn, oy = ay * invn, oz = az * invn, ow = aw * invn;
    size_t base = (size_t)v * DIM + l * 4;
    if (unxt) {
        float4 o = {ox, oy, oz, ow};
        *(float4*)(unxt + base) = o;
    }
    const float4 ri = *(const float4*)(resin + base);
    float4 ro = {ri.x + ox, ri.y + oy, ri.z + oz, ri.w + ow};
    *(float4*)(resout + base) = ro;
}

extern "C" void kernel_launch(void* const* d_in, const int* in_sizes, int n_in,
                              void* d_out, int out_size, void* d_ws, size_t ws_size,
                              hipStream_t stream) {
    const float* user_emb   = (const float*)d_in[0];
    const float* entity_emb = (const float*)d_in[1];
    const float* rel        = (const float*)d_in[2];
    const float* W_Q        = (const float*)d_in[3];
    const float* iwin       = (const float*)d_in[4];
    const int* ehead        = (const int*)d_in[5];
    const int* etail        = (const int*)d_in[6];
    const int* etype        = (const int*)d_in[7];
    const int* iuser        = (const int*)d_in[8];
    const int* iitem        = (const int*)d_in[9];

    float* out        = (float*)d_out;
    float* u_res      = out;                                   // [NUSERS, 64]
    float* e_res      = out + (size_t)NUSERS * DIM;            // [NENT, 64]
    float* edge_score = out + (size_t)(NUSERS + NENT) * DIM;   // [EKG]
    float* item_sum   = edge_score + EKG;                      // [NITEMS]

    // workspace carve (bump allocator, 256B aligned)
    char* w = (char*)d_ws;
    auto alloc = [&](size_t bytes) -> void* {
        void* p = (void*)w;
        w += (bytes + 255) & ~(size_t)255;
        return p;
    };
    float* P     = (float*)alloc((size_t)NENT * DIM * 4);
    float* eA    = (float*)alloc((size_t)NENT * DIM * 4);
    float* uA    = (float*)alloc((size_t)NUSERS * DIM * 4);
    float* att   = (float*)alloc((size_t)2 * EKG * 4);
    float* logit = (float*)alloc((size_t)EKG * 4);
    int* hoff    = (int*)alloc((NENT + 1) * 4);
    int* uoff    = (int*)alloc((NUSERS + 1) * 4);
    int* ioff    = (int*)alloc((NENT + 1) * 4);
    int* cnth    = (int*)alloc(NENT * 4);
    int* cntu    = (int*)alloc(NUSERS * 4);
    int* cnti    = (int*)alloc(NENT * 4);
    int* heid    = (int*)alloc(EKG * 4);
    int* hhead   = (int*)alloc(EKG * 4);
    int* htail   = (int*)alloc(EKG * 4);
    int* htype   = (int*)alloc(EKG * 4);
    int* uitem   = (int*)alloc(EUI * 4);
    float* uw    = (float*)alloc(EUI * 4);
    int* iuserc  = (int*)alloc(EUI * 4);
    float* iw2   = (float*)alloc(EUI * 4);
    (void)ws_size; (void)in_sizes; (void)n_in; (void)out_size;

    hipMemsetAsync(cnth, 0, NENT * 4, stream);
    hipMemsetAsync(cntu, 0, NUSERS * 4, stream);
    hipMemsetAsync(cnti, 0, NENT * 4, stream);
    hipMemsetAsync(item_sum, 0, NITEMS * 4, stream);

    // CSR build
    count_kernel<<<(EKG + 255) / 256, 256, 0, stream>>>(ehead, iuser, iitem, cnth, cntu, cnti);
    scan_excl_kernel<<<1, 256, 0, stream>>>(cnth, hoff, NENT);
    scan_excl_kernel<<<1, 256, 0, stream>>>(cntu, uoff, NUSERS);
    scan_excl_kernel<<<1, 256, 0, stream>>>(cnti, ioff, NENT);
    fill_kernel<<<(EKG + 255) / 256, 256, 0, stream>>>(ehead, etail, etype, iuser, iitem, iwin,
                                                       cnth, cntu, cnti, heid, hhead, htail, htype,
                                                       uitem, uw, iuserc, iw2);

    // ---- hop 0 (shares attention pass with Part A) ----
    gemm_wq_kernel<<<NENT / 16, 256, 0, stream>>>(entity_emb, W_Q, P);
    attn_kernel<<<EKG / 16, 256, 0, stream>>>(P, rel, hhead, htail, htype, att, logit);
    parta_kernel<<<(NENT + 255) / 256, 256, 0, stream>>>(logit, hoff, heid, htail, edge_score,
                                                         item_sum);
    hsm_kernel<<<(NENT + 255) / 256, 256, 0, stream>>>(att, hoff);
    agge_kernel<<<NENT / 16, 256, 0, stream>>>(entity_emb, user_emb, rel, att, hoff, htail, htype,
                                               ioff, iuserc, iw2, entity_emb, e_res, eA);
    aggu_kernel<<<NUSERS / 16, 256, 0, stream>>>(entity_emb, uoff, uitem, uw, user_emb, u_res, uA);

    // ---- hop 1 ----
    gemm_wq_kernel<<<NENT / 16, 256, 0, stream>>>(eA, W_Q, P);
    attn_kernel<<<EKG / 16, 256, 0, stream>>>(P, rel, hhead, htail, htype, att, nullptr);
    hsm_kernel<<<(NENT + 255) / 256, 256, 0, stream>>>(att, hoff);
    agge_kernel<<<NENT / 16, 256, 0, stream>>>(eA, uA, rel, att, hoff, htail, htype, ioff, iuserc,
                                               iw2, e_res, e_res, nullptr);
    aggu_kernel<<<NUSERS / 16, 256, 0, stream>>>(eA, uoff, uitem, uw, u_res, u_res, nullptr);
}

// Round 2
// 565.122 us; speedup vs baseline: 1.5960x; 1.5960x over previous
//
#include <hip/hip_runtime.h>
#include <math.h>

#define NUSERS 40000
#define NENT   80000
#define NITEMS 30000
#define DIM    64
#define EKG    800000
#define EUI    600000
#define NTOT   (NENT + NUSERS + NENT)   // 200000 combined count slots
#define UBASE  NENT                      // user counts start
#define IBASE  (NENT + NUSERS)           // item-side counts start
#define CAP    64                        // per-node LDS logit capacity

// ---------- helpers ----------
static __device__ __forceinline__ float grp16_sum(float v) {
    v += __shfl_xor(v, 1);
    v += __shfl_xor(v, 2);
    v += __shfl_xor(v, 4);
    v += __shfl_xor(v, 8);
    return v;
}

// ---------- CSR build ----------
__global__ void count_kernel(const int* __restrict__ ehead,
                             const int* __restrict__ iuser,
                             const int* __restrict__ iitem,
                             int* __restrict__ cnt) {
    int e = blockIdx.x * blockDim.x + threadIdx.x;
    if (e < EKG) atomicAdd(&cnt[ehead[e]], 1);
    if (e < EUI) {
        atomicAdd(&cnt[UBASE + iuser[e]], 1);
        atomicAdd(&cnt[IBASE + iitem[e]], 1);
    }
}

#define SCHUNK 2048
#define SBLOCKS ((NTOT + SCHUNK - 1) / SCHUNK)  // 98

__global__ void scanA_kernel(const int* __restrict__ cnt, int* __restrict__ bsum) {
    int b = blockIdx.x, tid = threadIdx.x;
    int base = b * SCHUNK + tid * 8;
    int ts = 0;
#pragma unroll
    for (int k = 0; k < 8; k++) {
        int i = base + k;
        ts += (i < NTOT) ? cnt[i] : 0;
    }
#pragma unroll
    for (int d = 1; d < 64; d <<= 1) ts += __shfl_xor(ts, d);
    __shared__ int ws[4];
    if ((tid & 63) == 0) ws[tid >> 6] = ts;
    __syncthreads();
    if (tid == 0) bsum[b] = ws[0] + ws[1] + ws[2] + ws[3];
}

// 1 block, 64 threads: exclusive scan of bsum -> bpre; off[NTOT] = total
__global__ void scanB_kernel(const int* __restrict__ bsum, int* __restrict__ bpre,
                             int* __restrict__ off) {
    int lane = threadIdx.x;
    int carry = 0;
    for (int base = 0; base < SBLOCKS; base += 64) {
        int i = base + lane;
        int x = (i < SBLOCKS) ? bsum[i] : 0;
        int inc = x;
#pragma unroll
        for (int d = 1; d < 64; d <<= 1) {
            int t = __shfl_up(inc, d);
            if (lane >= d) inc += t;
        }
        if (i < SBLOCKS) bpre[i] = carry + inc - x;
        carry += __shfl(inc, 63);
    }
    if (lane == 0) off[NTOT] = carry;
}

__global__ void scanC_kernel(const int* __restrict__ cnt, const int* __restrict__ bpre,
                             int* __restrict__ off, int* __restrict__ cur) {
    __shared__ int wtot[4];
    int b = blockIdx.x, tid = threadIdx.x, lane = tid & 63, wid = tid >> 6;
    int base = b * SCHUNK + tid * 8;
    int vals[8];
    int ts = 0;
#pragma unroll
    for (int k = 0; k < 8; k++) {
        int i = base + k;
        int x = (i < NTOT) ? cnt[i] : 0;
        vals[k] = ts;
        ts += x;
    }
    int inc = ts;
#pragma unroll
    for (int d = 1; d < 64; d <<= 1) {
        int t = __shfl_up(inc, d);
        if (lane >= d) inc += t;
    }
    if (lane == 63) wtot[wid] = inc;
    __syncthreads();
    int wbase = 0;
    for (int w = 0; w < wid; w++) wbase += wtot[w];
    int tbase = bpre[b] + wbase + (inc - ts);
#pragma unroll
    for (int k = 0; k < 8; k++) {
        int i = base + k;
        if (i < NTOT) {
            int e = tbase + vals[k];
            off[i] = e;
            cur[i] = e;
        }
    }
}

__global__ void fill_kernel(const int* __restrict__ ehead, const int* __restrict__ etail,
                            const int* __restrict__ etype,
                            const int* __restrict__ iuser, const int* __restrict__ iitem,
                            const float* __restrict__ iwin,
                            int* __restrict__ cur,
                            int4* __restrict__ kgpack,
                            int2* __restrict__ upack, int2* __restrict__ ipack) {
    int e = blockIdx.x * blockDim.x + threadIdx.x;
    if (e < EKG) {
        int h = ehead[e];
        int p = atomicAdd(&cur[h], 1);
        kgpack[p] = make_int4(etail[e], etype[e] - 1, e, 0);
    }
    if (e < EUI) {
        int u = iuser[e], it = iitem[e];
        int wbits = __float_as_int(iwin[e]);
        int pu = atomicAdd(&cur[UBASE + u], 1) - EKG;
        upack[pu] = make_int2(it, wbits);
        int pi = atomicAdd(&cur[IBASE + it], 1) - (EKG + EUI);
        ipack[pi] = make_int2(u, wbits);
    }
}

// ---------- P = X @ W_Q ----------
__global__ void gemm_wq_kernel(const float* __restrict__ X, const float* __restrict__ W,
                               float* __restrict__ P) {
    __shared__ float Wl[64 * 64];
    int tid = threadIdx.x;
    for (int i = tid; i < 64 * 64; i += 256) Wl[i] = W[i];
    __syncthreads();
    int rloc = tid >> 4;
    int c4 = (tid & 15) * 4;
    int row = blockIdx.x * 16 + rloc;
    const float* x = X + (size_t)row * DIM;
    float ax = 0, ay = 0, az = 0, aw = 0;
#pragma unroll 8
    for (int d = 0; d < 64; d++) {
        float xv = x[d];
        const float4 w = *(const float4*)&Wl[d * 64 + c4];
        ax += xv * w.x;
        ay += xv * w.y;
        az += xv * w.z;
        aw += xv * w.w;
    }
    float4 o = {ax, ay, az, aw};
    *(float4*)&P[(size_t)row * DIM + c4] = o;
}

// ---------- fused hop: attn + seg-softmax + aggregate + norm + residual ----------
// group of 16 lanes per node; v < NENT: entity path (+Part A when HOP0); else user path.
template <bool HOP0>
__global__ void hop_kernel(const float* __restrict__ P, const float* __restrict__ ecur,
                           const float* __restrict__ ucur, const float* __restrict__ rel,
                           const int* __restrict__ off,
                           const int4* __restrict__ kgpack,
                           const int2* __restrict__ upack, const int2* __restrict__ ipack,
                           const float* __restrict__ e_resin, float* __restrict__ e_resout,
                           const float* __restrict__ u_resin, float* __restrict__ u_resout,
                           float* __restrict__ enxt, float* __restrict__ unxt,
                           float* __restrict__ edge_score, float* __restrict__ item_sum) {
    __shared__ float latt[16][2][CAP + 1];
    int tid = threadIdx.x;
    int g = tid >> 4, l = tid & 15, h = l >> 3;
    int v = blockIdx.x * 16 + g;
    const float sc = 0.17677669529663687f;  // 1/sqrt(32)
    float ax = 0, ay = 0, az = 0, aw = 0;
    size_t basei;
    const float* resin;
    float* resout;
    float* nxt;

    if (v < NENT) {
        int o0 = off[v], o1 = off[v + 1];
        int deg = o1 - o0;
        const float4 q = *(const float4*)(P + (size_t)v * DIM + l * 4);
        float m_h = -INFINITY, s_h = 0.f;
        float m_lm = -INFINITY, s_lm = 0.f, lsum = 0.f;
        for (int j = o0; j < o1; j++) {
            int4 kp = kgpack[j];
            const float4 k = *(const float4*)(P + (size_t)kp.x * DIM + l * 4);
            const float4 rv = *(const float4*)(rel + kp.y * DIM + l * 4);
            float part = q.x * k.x * rv.x + q.y * k.y * rv.y + q.z * k.z * rv.z + q.w * k.w * rv.w;
            part += __shfl_xor(part, 1);
            part += __shfl_xor(part, 2);
            part += __shfl_xor(part, 4);
            part *= sc;
            int idx = j - o0;
            if (idx < CAP) {
                if (l == 0) latt[g][0][idx] = part;
                else if (l == 8) latt[g][1][idx] = part;
            }
            float mn = fmaxf(m_h, part);
            s_h = s_h * __expf(m_h - mn) + __expf(part - mn);
            m_h = mn;
            if (HOP0) {
                float other = __shfl_xor(part, 8);
                float lm = 0.5f * (part + other);
                float mn2 = fmaxf(m_lm, lm);
                s_lm = s_lm * __expf(m_lm - mn2) + __expf(lm - mn2);
                m_lm = mn2;
                lsum += lm;
            }
        }
        float inv_sh = 1.0f / (s_h + 1e-16f);
        float inv_slm = HOP0 ? 1.0f / (s_lm + 1e-16f) : 0.f;
        for (int j = o0; j < o1; j++) {
            int4 kp = kgpack[j];
            int idx = j - o0;
            float lh;
            const float4 rv = *(const float4*)(rel + kp.y * DIM + l * 4);
            if (idx < CAP) {
                lh = latt[g][h][idx];
            } else {  // rare overflow: recompute logit
                const float4 k = *(const float4*)(P + (size_t)kp.x * DIM + l * 4);
                float part = q.x * k.x * rv.x + q.y * k.y * rv.y + q.z * k.z * rv.z +
                             q.w * k.w * rv.w;
                part += __shfl_xor(part, 1);
                part += __shfl_xor(part, 2);
                part += __shfl_xor(part, 4);
                lh = part * sc;
            }
            float s_att = __expf(lh - m_h) * inv_sh;
            const float4 ev = *(const float4*)(ecur + (size_t)kp.x * DIM + l * 4);
            ax += ev.x * rv.x * s_att;
            ay += ev.y * rv.y * s_att;
            az += ev.z * rv.z * s_att;
            aw += ev.w * rv.w * s_att;
            if (HOP0) {
                float other = __shfl_xor(lh, 8);
                float lm = 0.5f * (lh + other);
                if (l == 0) {
                    edge_score[kp.z] = __expf(lm - m_lm) * inv_slm * (float)deg;
                    if (kp.x < NITEMS) atomicAdd(&item_sum[kp.x], lm);
                }
            }
        }
        if (HOP0 && l == 0 && v < NITEMS && deg > 0) atomicAdd(&item_sum[v], lsum);
        // UI: users -> this entity
        int p0 = off[IBASE + v] - (EKG + EUI);
        int p1 = off[IBASE + v + 1] - (EKG + EUI);
        for (int j = p0; j < p1; j++) {
            int2 up = ipack[j];
            float w = __int_as_float(up.y);
            const float4 uv = *(const float4*)(ucur + (size_t)up.x * DIM + l * 4);
            ax += w * uv.x;
            ay += w * uv.y;
            az += w * uv.z;
            aw += w * uv.w;
        }
        basei = (size_t)v * DIM + l * 4;
        resin = e_resin;
        resout = e_resout;
        nxt = enxt;
    } else {
        int u = v - NENT;
        int p0 = off[UBASE + u] - EKG;
        int p1 = off[UBASE + u + 1] - EKG;
        for (int j = p0; j < p1; j++) {
            int2 up = upack[j];
            float w = __int_as_float(up.y);
            const float4 ev = *(const float4*)(ecur + (size_t)up.x * DIM + l * 4);
            ax += w * ev.x;
            ay += w * ev.y;
            az += w * ev.z;
            aw += w * ev.w;
        }
        basei = (size_t)u * DIM + l * 4;
        resin = u_resin;
        resout = u_resout;
        nxt = unxt;
    }

    float nsq = grp16_sum(ax * ax + ay * ay + az * az + aw * aw);
    float invn = 1.0f / fmaxf(sqrtf(nsq), 1e-12f);
    float ox = ax * invn, oy = ay * invn, oz = az * invn, ow = aw * invn;
    if (nxt) {
        float4 o = {ox, oy, oz, ow};
        *(float4*)(nxt + basei) = o;
    }
    const float4 ri = *(const float4*)(resin + basei);
    float4 ro = {ri.x + ox, ri.y + oy, ri.z + oz, ri.w + ow};
    *(float4*)(resout + basei) = ro;
}

extern "C" void kernel_launch(void* const* d_in, const int* in_sizes, int n_in,
                              void* d_out, int out_size, void* d_ws, size_t ws_size,
                              hipStream_t stream) {
    const float* user_emb   = (const float*)d_in[0];
    const float* entity_emb = (const float*)d_in[1];
    const float* rel        = (const float*)d_in[2];
    const float* W_Q        = (const float*)d_in[3];
    const float* iwin       = (const float*)d_in[4];
    const int* ehead        = (const int*)d_in[5];
    const int* etail        = (const int*)d_in[6];
    const int* etype        = (const int*)d_in[7];
    const int* iuser        = (const int*)d_in[8];
    const int* iitem        = (const int*)d_in[9];

    float* out        = (float*)d_out;
    float* u_res      = out;
    float* e_res      = out + (size_t)NUSERS * DIM;
    float* edge_score = out + (size_t)(NUSERS + NENT) * DIM;
    float* item_sum   = edge_score + EKG;

    char* w = (char*)d_ws;
    auto alloc = [&](size_t bytes) -> void* {
        void* p = (void*)w;
        w += (bytes + 255) & ~(size_t)255;
        return p;
    };
    float* P      = (float*)alloc((size_t)NENT * DIM * 4);
    float* eA     = (float*)alloc((size_t)NENT * DIM * 4);
    float* uA     = (float*)alloc((size_t)NUSERS * DIM * 4);
    int4* kgpack  = (int4*)alloc((size_t)EKG * 16);
    int2* upack   = (int2*)alloc((size_t)EUI * 8);
    int2* ipack   = (int2*)alloc((size_t)EUI * 8);
    int* cnt      = (int*)alloc((size_t)NTOT * 4);
    int* cur      = (int*)alloc((size_t)NTOT * 4);
    int* off      = (int*)alloc((size_t)(NTOT + 1) * 4);
    int* bsum     = (int*)alloc((size_t)SBLOCKS * 4);
    int* bpre     = (int*)alloc((size_t)SBLOCKS * 4);
    (void)ws_size; (void)in_sizes; (void)n_in; (void)out_size;

    hipMemsetAsync(cnt, 0, (size_t)NTOT * 4, stream);
    hipMemsetAsync(item_sum, 0, (size_t)NITEMS * 4, stream);

    // CSR build
    count_kernel<<<(EKG + 255) / 256, 256, 0, stream>>>(ehead, iuser, iitem, cnt);
    scanA_kernel<<<SBLOCKS, 256, 0, stream>>>(cnt, bsum);
    scanB_kernel<<<1, 64, 0, stream>>>(bsum, bpre, off);
    scanC_kernel<<<SBLOCKS, 256, 0, stream>>>(cnt, bpre, off, cur);
    fill_kernel<<<(EKG + 255) / 256, 256, 0, stream>>>(ehead, etail, etype, iuser, iitem, iwin,
                                                       cur, kgpack, upack, ipack);

    const int HOPG = (NENT + NUSERS) / 16;  // 7500 blocks

    // ---- hop 0 (includes Part A) ----
    gemm_wq_kernel<<<NENT / 16, 256, 0, stream>>>(entity_emb, W_Q, P);
    hop_kernel<true><<<HOPG, 256, 0, stream>>>(P, entity_emb, user_emb, rel, off, kgpack, upack,
                                               ipack, entity_emb, e_res, user_emb, u_res, eA, uA,
                                               edge_score, item_sum);

    // ---- hop 1 ----
    gemm_wq_kernel<<<NENT / 16, 256, 0, stream>>>(eA, W_Q, P);
    hop_kernel<false><<<HOPG, 256, 0, stream>>>(P, eA, uA, rel, off, kgpack, upack, ipack, e_res,
                                                e_res, u_res, u_res, nullptr, nullptr, nullptr,
                                                nullptr);
}

// Round 3
// 509.637 us; speedup vs baseline: 1.7698x; 1.1089x over previous
//
#include <hip/hip_runtime.h>
#include <math.h>

#define NUSERS 40000
#define NENT   80000
#define NITEMS 30000
#define DIM    64
#define EKG    800000
#define EUI    600000
#define NTOT   (NENT + NUSERS + NENT)   // 200000 combined count slots
#define UBASE  NENT                      // user counts start
#define IBASE  (NENT + NUSERS)           // item-side counts start

// ---------- helpers ----------
static __device__ __forceinline__ float grp16_sum(float v) {
    v += __shfl_xor(v, 1);
    v += __shfl_xor(v, 2);
    v += __shfl_xor(v, 4);
    v += __shfl_xor(v, 8);
    return v;
}

// ---------- CSR build ----------
__global__ void count_kernel(const int* __restrict__ ehead,
                             const int* __restrict__ iuser,
                             const int* __restrict__ iitem,
                             int* __restrict__ cnt) {
    int e = blockIdx.x * blockDim.x + threadIdx.x;
    if (e < EKG) atomicAdd(&cnt[__builtin_nontemporal_load(&ehead[e])], 1);
    if (e < EUI) {
        atomicAdd(&cnt[UBASE + __builtin_nontemporal_load(&iuser[e])], 1);
        atomicAdd(&cnt[IBASE + __builtin_nontemporal_load(&iitem[e])], 1);
    }
}

#define SCHUNK 2048
#define SBLOCKS ((NTOT + SCHUNK - 1) / SCHUNK)  // 98

__global__ void scanA_kernel(const int* __restrict__ cnt, int* __restrict__ bsum) {
    int b = blockIdx.x, tid = threadIdx.x;
    int base = b * SCHUNK + tid * 8;
    int ts = 0;
#pragma unroll
    for (int k = 0; k < 8; k++) {
        int i = base + k;
        ts += (i < NTOT) ? cnt[i] : 0;
    }
#pragma unroll
    for (int d = 1; d < 64; d <<= 1) ts += __shfl_xor(ts, d);
    __shared__ int ws[4];
    if ((tid & 63) == 0) ws[tid >> 6] = ts;
    __syncthreads();
    if (tid == 0) bsum[b] = ws[0] + ws[1] + ws[2] + ws[3];
}

__global__ void scanB_kernel(const int* __restrict__ bsum, int* __restrict__ bpre,
                             int* __restrict__ off) {
    int lane = threadIdx.x;
    int carry = 0;
    for (int base = 0; base < SBLOCKS; base += 64) {
        int i = base + lane;
        int x = (i < SBLOCKS) ? bsum[i] : 0;
        int inc = x;
#pragma unroll
        for (int d = 1; d < 64; d <<= 1) {
            int t = __shfl_up(inc, d);
            if (lane >= d) inc += t;
        }
        if (i < SBLOCKS) bpre[i] = carry + inc - x;
        carry += __shfl(inc, 63);
    }
    if (lane == 0) off[NTOT] = carry;
}

__global__ void scanC_kernel(const int* __restrict__ cnt, const int* __restrict__ bpre,
                             int* __restrict__ off, int* __restrict__ cur) {
    __shared__ int wtot[4];
    int b = blockIdx.x, tid = threadIdx.x, lane = tid & 63, wid = tid >> 6;
    int base = b * SCHUNK + tid * 8;
    int vals[8];
    int ts = 0;
#pragma unroll
    for (int k = 0; k < 8; k++) {
        int i = base + k;
        int x = (i < NTOT) ? cnt[i] : 0;
        vals[k] = ts;
        ts += x;
    }
    int inc = ts;
#pragma unroll
    for (int d = 1; d < 64; d <<= 1) {
        int t = __shfl_up(inc, d);
        if (lane >= d) inc += t;
    }
    if (lane == 63) wtot[wid] = inc;
    __syncthreads();
    int wbase = 0;
    for (int w = 0; w < wid; w++) wbase += wtot[w];
    int tbase = bpre[b] + wbase + (inc - ts);
#pragma unroll
    for (int k = 0; k < 8; k++) {
        int i = base + k;
        if (i < NTOT) {
            int e = tbase + vals[k];
            off[i] = e;
            cur[i] = e;
        }
    }
}

// ---- range-partitioned fills: scatter slice per pass fits per-XCD L2 ----
__global__ void fillKG_kernel(const int* __restrict__ ehead, const int* __restrict__ etail,
                              const int* __restrict__ etype, int* __restrict__ cur,
                              int4* __restrict__ kgpack, int lo, int hi) {
    int e = blockIdx.x * blockDim.x + threadIdx.x;
    if (e >= EKG) return;
    int h = __builtin_nontemporal_load(&ehead[e]);
    if (h < lo || h >= hi) return;
    int p = atomicAdd(&cur[h], 1);
    kgpack[p] = make_int4(__builtin_nontemporal_load(&etail[e]),
                          __builtin_nontemporal_load(&etype[e]) - 1, e, 0);
}

__global__ void fillUIu_kernel(const int* __restrict__ iuser, const int* __restrict__ iitem,
                               const float* __restrict__ iwin, int* __restrict__ cur,
                               int2* __restrict__ upack, int lo, int hi) {
    int e = blockIdx.x * blockDim.x + threadIdx.x;
    if (e >= EUI) return;
    int u = __builtin_nontemporal_load(&iuser[e]);
    if (u < lo || u >= hi) return;
    int p = atomicAdd(&cur[UBASE + u], 1) - EKG;
    upack[p] = make_int2(__builtin_nontemporal_load(&iitem[e]),
                         __float_as_int(__builtin_nontemporal_load(&iwin[e])));
}

__global__ void fillUIi_kernel(const int* __restrict__ iuser, const int* __restrict__ iitem,
                               const float* __restrict__ iwin, int* __restrict__ cur,
                               int2* __restrict__ ipack, int lo, int hi) {
    int e = blockIdx.x * blockDim.x + threadIdx.x;
    if (e >= EUI) return;
    int it = __builtin_nontemporal_load(&iitem[e]);
    if (it < lo || it >= hi) return;
    int p = atomicAdd(&cur[IBASE + it], 1) - (EKG + EUI);
    ipack[p] = make_int2(__builtin_nontemporal_load(&iuser[e]),
                         __float_as_int(__builtin_nontemporal_load(&iwin[e])));
}

// ---------- P = X @ W_Q ----------
__global__ void gemm_wq_kernel(const float* __restrict__ X, const float* __restrict__ W,
                               float* __restrict__ P) {
    __shared__ float Wl[64 * 64];
    int tid = threadIdx.x;
    for (int i = tid; i < 64 * 64; i += 256) Wl[i] = W[i];
    __syncthreads();
    int rloc = tid >> 4;
    int c4 = (tid & 15) * 4;
    int row = blockIdx.x * 16 + rloc;
    const float* x = X + (size_t)row * DIM;
    float ax = 0, ay = 0, az = 0, aw = 0;
#pragma unroll 8
    for (int d = 0; d < 64; d++) {
        float xv = x[d];
        const float4 w = *(const float4*)&Wl[d * 64 + c4];
        ax += xv * w.x;
        ay += xv * w.y;
        az += xv * w.z;
        aw += xv * w.w;
    }
    float4 o = {ax, ay, az, aw};
    *(float4*)&P[(size_t)row * DIM + c4] = o;
}

// ---------- fused hop: flash-style single-pass attn+softmax+aggregate+norm+residual ----------
template <bool HOP0>
__global__ void hop_kernel(const float* __restrict__ P, const float* __restrict__ ecur,
                           const float* __restrict__ ucur, const float* __restrict__ rel,
                           const int* __restrict__ off,
                           const int4* __restrict__ kgpack,
                           const int2* __restrict__ upack, const int2* __restrict__ ipack,
                           const float* __restrict__ e_resin, float* __restrict__ e_resout,
                           const float* __restrict__ u_resin, float* __restrict__ u_resout,
                           float* __restrict__ enxt, float* __restrict__ unxt,
                           float* __restrict__ logit,
                           float* __restrict__ edge_score, float* __restrict__ item_sum) {
    __shared__ float srel[7 * DIM];
    int tid = threadIdx.x;
    for (int i = tid; i < 7 * DIM; i += 256) srel[i] = rel[i];
    __syncthreads();
    int g = tid >> 4, l = tid & 15;
    int v = blockIdx.x * 16 + g;
    const float sc = 0.17677669529663687f;  // 1/sqrt(32)
    float ax = 0, ay = 0, az = 0, aw = 0;
    size_t basei;
    const float* resin;
    float* resout;
    float* nxt;

    if (v < NENT) {
        int o0 = off[v], o1 = off[v + 1];
        int deg = o1 - o0;
        const float4 q = *(const float4*)(P + (size_t)v * DIM + l * 4);
        float m_h = -INFINITY, s_h = 0.f;
        float m_lm = -INFINITY, s_lm = 0.f, lsum = 0.f;
        for (int j = o0; j < o1; j++) {
            int4 kp = kgpack[j];
            const float4 k = *(const float4*)(P + (size_t)kp.x * DIM + l * 4);
            const float4 rv = *(const float4*)(srel + kp.y * DIM + l * 4);
            const float4 ev = *(const float4*)(ecur + (size_t)kp.x * DIM + l * 4);
            float part = q.x * k.x * rv.x + q.y * k.y * rv.y + q.z * k.z * rv.z + q.w * k.w * rv.w;
            part += __shfl_xor(part, 1);
            part += __shfl_xor(part, 2);
            part += __shfl_xor(part, 4);
            part *= sc;  // per-head logit (uniform within 8-lane half)
            float mn = fmaxf(m_h, part);
            float f = __expf(m_h - mn);
            float w = __expf(part - mn);
            s_h = s_h * f + w;
            ax = ax * f + w * ev.x * rv.x;
            ay = ay * f + w * ev.y * rv.y;
            az = az * f + w * ev.z * rv.z;
            aw = aw * f + w * ev.w * rv.w;
            m_h = mn;
            if (HOP0) {
                float other = __shfl_xor(part, 8);
                float lm = 0.5f * (part + other);  // uniform across 16 lanes
                float mn2 = fmaxf(m_lm, lm);
                s_lm = s_lm * __expf(m_lm - mn2) + __expf(lm - mn2);
                m_lm = mn2;
                lsum += lm;
                logit[j] = lm;  // all lanes store (same value) -> own-store visibility
                if (l == 0 && kp.x < NITEMS) atomicAdd(&item_sum[kp.x], lm);
            }
        }
        float inv_sh = 1.0f / (s_h + 1e-16f);
        ax *= inv_sh;
        ay *= inv_sh;
        az *= inv_sh;
        aw *= inv_sh;
        if (HOP0) {
            if (l == 0 && v < NITEMS && deg > 0) atomicAdd(&item_sum[v], lsum);
            float inv_slm = 1.0f / (s_lm + 1e-16f);
            float degf = (float)deg;
            for (int j = o0 + l; j < o1; j += 16) {
                int eid = kgpack[j].z;
                float lm = logit[j];
                edge_score[eid] = __expf(lm - m_lm) * inv_slm * degf;
            }
        }
        // UI: users -> this entity
        int p0 = off[IBASE + v] - (EKG + EUI);
        int p1 = off[IBASE + v + 1] - (EKG + EUI);
        for (int j = p0; j < p1; j++) {
            int2 up = ipack[j];
            float w = __int_as_float(up.y);
            const float4 uv = *(const float4*)(ucur + (size_t)up.x * DIM + l * 4);
            ax += w * uv.x;
            ay += w * uv.y;
            az += w * uv.z;
            aw += w * uv.w;
        }
        basei = (size_t)v * DIM + l * 4;
        resin = e_resin;
        resout = e_resout;
        nxt = enxt;
    } else {
        int u = v - NENT;
        int p0 = off[UBASE + u] - EKG;
        int p1 = off[UBASE + u + 1] - EKG;
        for (int j = p0; j < p1; j++) {
            int2 up = upack[j];
            float w = __int_as_float(up.y);
            const float4 ev = *(const float4*)(ecur + (size_t)up.x * DIM + l * 4);
            ax += w * ev.x;
            ay += w * ev.y;
            az += w * ev.z;
            aw += w * ev.w;
        }
        basei = (size_t)u * DIM + l * 4;
        resin = u_resin;
        resout = u_resout;
        nxt = unxt;
    }

    float nsq = grp16_sum(ax * ax + ay * ay + az * az + aw * aw);
    float invn = 1.0f / fmaxf(sqrtf(nsq), 1e-12f);
    float ox = ax * invn, oy = ay * invn, oz = az * invn, ow = aw * invn;
    if (nxt) {
        float4 o = {ox, oy, oz, ow};
        *(float4*)(nxt + basei) = o;
    }
    const float4 ri = *(const float4*)(resin + basei);
    float4 ro = {ri.x + ox, ri.y + oy, ri.z + oz, ri.w + ow};
    *(float4*)(resout + basei) = ro;
}

extern "C" void kernel_launch(void* const* d_in, const int* in_sizes, int n_in,
                              void* d_out, int out_size, void* d_ws, size_t ws_size,
                              hipStream_t stream) {
    const float* user_emb   = (const float*)d_in[0];
    const float* entity_emb = (const float*)d_in[1];
    const float* rel        = (const float*)d_in[2];
    const float* W_Q        = (const float*)d_in[3];
    const float* iwin       = (const float*)d_in[4];
    const int* ehead        = (const int*)d_in[5];
    const int* etail        = (const int*)d_in[6];
    const int* etype        = (const int*)d_in[7];
    const int* iuser        = (const int*)d_in[8];
    const int* iitem        = (const int*)d_in[9];

    float* out        = (float*)d_out;
    float* u_res      = out;
    float* e_res      = out + (size_t)NUSERS * DIM;
    float* edge_score = out + (size_t)(NUSERS + NENT) * DIM;
    float* item_sum   = edge_score + EKG;

    char* w = (char*)d_ws;
    auto alloc = [&](size_t bytes) -> void* {
        void* p = (void*)w;
        w += (bytes + 255) & ~(size_t)255;
        return p;
    };
    float* P      = (float*)alloc((size_t)NENT * DIM * 4);
    float* eA     = (float*)alloc((size_t)NENT * DIM * 4);
    float* uA     = (float*)alloc((size_t)NUSERS * DIM * 4);
    int4* kgpack  = (int4*)alloc((size_t)EKG * 16);
    int2* upack   = (int2*)alloc((size_t)EUI * 8);
    int2* ipack   = (int2*)alloc((size_t)EUI * 8);
    float* logit  = (float*)alloc((size_t)EKG * 4);
    int* cnt      = (int*)alloc((size_t)NTOT * 4);
    int* cur      = (int*)alloc((size_t)NTOT * 4);
    int* off      = (int*)alloc((size_t)(NTOT + 1) * 4);
    int* bsum     = (int*)alloc((size_t)SBLOCKS * 4);
    int* bpre     = (int*)alloc((size_t)SBLOCKS * 4);
    (void)ws_size; (void)in_sizes; (void)n_in; (void)out_size;

    hipMemsetAsync(cnt, 0, (size_t)NTOT * 4, stream);
    hipMemsetAsync(item_sum, 0, (size_t)NITEMS * 4, stream);

    // CSR build
    count_kernel<<<(EKG + 255) / 256, 256, 0, stream>>>(ehead, iuser, iitem, cnt);
    scanA_kernel<<<SBLOCKS, 256, 0, stream>>>(cnt, bsum);
    scanB_kernel<<<1, 64, 0, stream>>>(bsum, bpre, off);
    scanC_kernel<<<SBLOCKS, 256, 0, stream>>>(cnt, bpre, off, cur);

    const int KGG = (EKG + 255) / 256, UIG = (EUI + 255) / 256;
    for (int p = 0; p < 4; p++)
        fillKG_kernel<<<KGG, 256, 0, stream>>>(ehead, etail, etype, cur, kgpack,
                                               p * 20000, (p + 1) * 20000);
    for (int p = 0; p < 2; p++)
        fillUIu_kernel<<<UIG, 256, 0, stream>>>(iuser, iitem, iwin, cur, upack,
                                                p * 20000, (p + 1) * 20000);
    for (int p = 0; p < 2; p++)
        fillUIi_kernel<<<UIG, 256, 0, stream>>>(iuser, iitem, iwin, cur, ipack,
                                                p * 40000, (p + 1) * 40000);

    const int HOPG = (NENT + NUSERS) / 16;  // 7500 blocks

    // ---- hop 0 (includes Part A) ----
    gemm_wq_kernel<<<NENT / 16, 256, 0, stream>>>(entity_emb, W_Q, P);
    hop_kernel<true><<<HOPG, 256, 0, stream>>>(P, entity_emb, user_emb, rel, off, kgpack, upack,
                                               ipack, entity_emb, e_res, user_emb, u_res, eA, uA,
                                               logit, edge_score, item_sum);

    // ---- hop 1 ----
    gemm_wq_kernel<<<NENT / 16, 256, 0, stream>>>(eA, W_Q, P);
    hop_kernel<false><<<HOPG, 256, 0, stream>>>(P, eA, uA, rel, off, kgpack, upack, ipack, e_res,
                                                e_res, u_res, u_res, nullptr, nullptr, nullptr,
                                                nullptr, nullptr);
}

// Round 4
// 392.846 us; speedup vs baseline: 2.2959x; 1.2973x over previous
//
#include <hip/hip_runtime.h>
#include <math.h>

#define NUSERS 40000
#define NENT   80000
#define NITEMS 30000
#define DIM    64
#define EKG    800000
#define EUI    600000
#define NTOT   (NENT + NUSERS + NENT)   // 200000 combined count slots
#define UBASE  NENT                      // user counts start
#define IBASE  (NENT + NUSERS)           // item-side counts start

// ---------- bf16 helpers (RNE) ----------
struct __align__(8) us4 { unsigned short x, y, z, w; };
static __device__ __forceinline__ float b2f(unsigned short b) {
    return __uint_as_float(((unsigned)b) << 16);
}
static __device__ __forceinline__ unsigned short f2b(float f) {
    unsigned u = __float_as_uint(f);
    return (unsigned short)((u + 0x7FFFu + ((u >> 16) & 1u)) >> 16);
}
static __device__ __forceinline__ float4 ld4b(const unsigned short* p) {
    us4 v = *(const us4*)p;
    return make_float4(b2f(v.x), b2f(v.y), b2f(v.z), b2f(v.w));
}
static __device__ __forceinline__ void st4b(unsigned short* p, float a, float b, float c, float d) {
    us4 v = {f2b(a), f2b(b), f2b(c), f2b(d)};
    *(us4*)p = v;
}

static __device__ __forceinline__ float grp16_sum(float v) {
    v += __shfl_xor(v, 1);
    v += __shfl_xor(v, 2);
    v += __shfl_xor(v, 4);
    v += __shfl_xor(v, 8);
    return v;
}

// ---------- CSR build: count + per-edge rank ----------
__global__ void count_kernel(const int* __restrict__ ehead,
                             const int* __restrict__ iuser,
                             const int* __restrict__ iitem,
                             int* __restrict__ cnt,
                             int* __restrict__ rankK, int* __restrict__ rankU,
                             int* __restrict__ rankI) {
    int e = blockIdx.x * blockDim.x + threadIdx.x;
    if (e < EKG) rankK[e] = atomicAdd(&cnt[__builtin_nontemporal_load(&ehead[e])], 1);
    if (e < EUI) {
        rankU[e] = atomicAdd(&cnt[UBASE + __builtin_nontemporal_load(&iuser[e])], 1);
        rankI[e] = atomicAdd(&cnt[IBASE + __builtin_nontemporal_load(&iitem[e])], 1);
    }
}

#define SCHUNK 2048
#define SBLOCKS ((NTOT + SCHUNK - 1) / SCHUNK)  // 98

__global__ void scanA_kernel(const int* __restrict__ cnt, int* __restrict__ bsum) {
    int b = blockIdx.x, tid = threadIdx.x;
    int base = b * SCHUNK + tid * 8;
    int ts = 0;
#pragma unroll
    for (int k = 0; k < 8; k++) {
        int i = base + k;
        ts += (i < NTOT) ? cnt[i] : 0;
    }
#pragma unroll
    for (int d = 1; d < 64; d <<= 1) ts += __shfl_xor(ts, d);
    __shared__ int ws[4];
    if ((tid & 63) == 0) ws[tid >> 6] = ts;
    __syncthreads();
    if (tid == 0) bsum[b] = ws[0] + ws[1] + ws[2] + ws[3];
}

__global__ void scanB_kernel(const int* __restrict__ bsum, int* __restrict__ bpre,
                             int* __restrict__ off) {
    int lane = threadIdx.x;
    int carry = 0;
    for (int base = 0; base < SBLOCKS; base += 64) {
        int i = base + lane;
        int x = (i < SBLOCKS) ? bsum[i] : 0;
        int inc = x;
#pragma unroll
        for (int d = 1; d < 64; d <<= 1) {
            int t = __shfl_up(inc, d);
            if (lane >= d) inc += t;
        }
        if (i < SBLOCKS) bpre[i] = carry + inc - x;
        carry += __shfl(inc, 63);
    }
    if (lane == 0) off[NTOT] = carry;
}

__global__ void scanC_kernel(const int* __restrict__ cnt, const int* __restrict__ bpre,
                             int* __restrict__ off) {
    __shared__ int wtot[4];
    int b = blockIdx.x, tid = threadIdx.x, lane = tid & 63, wid = tid >> 6;
    int base = b * SCHUNK + tid * 8;
    int vals[8];
    int ts = 0;
#pragma unroll
    for (int k = 0; k < 8; k++) {
        int i = base + k;
        int x = (i < NTOT) ? cnt[i] : 0;
        vals[k] = ts;
        ts += x;
    }
    int inc = ts;
#pragma unroll
    for (int d = 1; d < 64; d <<= 1) {
        int t = __shfl_up(inc, d);
        if (lane >= d) inc += t;
    }
    if (lane == 63) wtot[wid] = inc;
    __syncthreads();
    int wbase = 0;
    for (int w = 0; w < wid; w++) wbase += wtot[w];
    int tbase = bpre[b] + wbase + (inc - ts);
#pragma unroll
    for (int k = 0; k < 8; k++) {
        int i = base + k;
        if (i < NTOT) off[i] = tbase + vals[k];
    }
}

// ---- atomic-free range-partitioned fills (scatter slice stays L2-resident) ----
__global__ void fillKG_kernel(const int* __restrict__ ehead, const int* __restrict__ etail,
                              const int* __restrict__ etype, const int* __restrict__ rankK,
                              const int* __restrict__ off,
                              int* __restrict__ tt, int* __restrict__ eid, int lo, int hi) {
    int e = blockIdx.x * blockDim.x + threadIdx.x;
    if (e >= EKG) return;
    int h = __builtin_nontemporal_load(&ehead[e]);
    if (h < lo || h >= hi) return;
    int p = off[h] + __builtin_nontemporal_load(&rankK[e]);
    tt[p] = __builtin_nontemporal_load(&etail[e]) |
            ((__builtin_nontemporal_load(&etype[e]) - 1) << 20);
    eid[p] = e;
}

__global__ void fillUIu_kernel(const int* __restrict__ iuser, const int* __restrict__ iitem,
                               const float* __restrict__ iwin, const int* __restrict__ rankU,
                               const int* __restrict__ off,
                               int2* __restrict__ upack, int lo, int hi) {
    int e = blockIdx.x * blockDim.x + threadIdx.x;
    if (e >= EUI) return;
    int u = __builtin_nontemporal_load(&iuser[e]);
    if (u < lo || u >= hi) return;
    int p = off[UBASE + u] - EKG + __builtin_nontemporal_load(&rankU[e]);
    upack[p] = make_int2(__builtin_nontemporal_load(&iitem[e]),
                         __float_as_int(__builtin_nontemporal_load(&iwin[e])));
}

__global__ void fillUIi_kernel(const int* __restrict__ iuser, const int* __restrict__ iitem,
                               const float* __restrict__ iwin, const int* __restrict__ rankI,
                               const int* __restrict__ off,
                               int2* __restrict__ ipack, int lo, int hi) {
    int e = blockIdx.x * blockDim.x + threadIdx.x;
    if (e >= EUI) return;
    int it = __builtin_nontemporal_load(&iitem[e]);
    if (it < lo || it >= hi) return;
    int p = off[IBASE + it] - (EKG + EUI) + __builtin_nontemporal_load(&rankI[e]);
    ipack[p] = make_int2(__builtin_nontemporal_load(&iuser[e]),
                         __float_as_int(__builtin_nontemporal_load(&iwin[e])));
}

// ---------- f32 -> bf16 table convert ----------
__global__ void cvt_kernel(const float* __restrict__ in, unsigned short* __restrict__ out,
                           int n4) {
    int i = blockIdx.x * blockDim.x + threadIdx.x;
    if (i >= n4) return;
    float4 v = *(const float4*)(in + (size_t)i * 4);
    st4b(out + (size_t)i * 4, v.x, v.y, v.z, v.w);
}

// ---------- P = X @ W_Q  (bf16 out; MODE 0: f32 in + also emit bf16 copy of X) ----------
template <int MODE>
__global__ void gemm_wq_kernel(const float* __restrict__ Xf,
                               const unsigned short* __restrict__ Xb_in,
                               const float* __restrict__ W,
                               unsigned short* __restrict__ Pb,
                               unsigned short* __restrict__ Xb_out) {
    __shared__ float Wl[64 * 64];
    int tid = threadIdx.x;
    for (int i = tid; i < 64 * 64; i += 256) Wl[i] = W[i];
    __syncthreads();
    int rloc = tid >> 4;
    int c4 = (tid & 15) * 4;
    int row = blockIdx.x * 16 + rloc;
    float ax = 0, ay = 0, az = 0, aw = 0;
#pragma unroll 8
    for (int d = 0; d < 64; d++) {
        float xv = (MODE == 0) ? Xf[(size_t)row * DIM + d] : b2f(Xb_in[(size_t)row * DIM + d]);
        const float4 w = *(const float4*)&Wl[d * 64 + c4];
        ax += xv * w.x;
        ay += xv * w.y;
        az += xv * w.z;
        aw += xv * w.w;
    }
    st4b(Pb + (size_t)row * DIM + c4, ax, ay, az, aw);
    if (MODE == 0) {
        const float4 xx = *(const float4*)(Xf + (size_t)row * DIM + c4);
        st4b(Xb_out + (size_t)row * DIM + c4, xx.x, xx.y, xx.z, xx.w);
    }
}

// ---------- fused hop: flash-style attn+softmax+aggregate+norm (+residual on hop1) ----------
template <bool HOP0>
__global__ void hop_kernel(const unsigned short* __restrict__ Pb,
                           const unsigned short* __restrict__ eb,
                           const unsigned short* __restrict__ ub,
                           const float* __restrict__ rel,
                           const int* __restrict__ off,
                           const int* __restrict__ tt, const int* __restrict__ eid,
                           const int2* __restrict__ upack, const int2* __restrict__ ipack,
                           const float* __restrict__ ebase, const float* __restrict__ ubase,
                           const unsigned short* __restrict__ eprevb,
                           const unsigned short* __restrict__ uprevb,
                           float* __restrict__ e_res, float* __restrict__ u_res,
                           unsigned short* __restrict__ enxtb, unsigned short* __restrict__ unxtb,
                           float* __restrict__ logit, float* __restrict__ edge_score,
                           float* __restrict__ item_sum) {
    __shared__ float srel[7 * DIM];
    int tid = threadIdx.x;
    for (int i = tid; i < 7 * DIM; i += 256) srel[i] = rel[i];
    __syncthreads();
    int g = tid >> 4, l = tid & 15;
    int v = blockIdx.x * 16 + g;
    const float sc = 0.17677669529663687f;  // 1/sqrt(32)
    float ax = 0, ay = 0, az = 0, aw = 0;

    if (v < NENT) {
        int o0 = off[v], o1 = off[v + 1];
        int deg = o1 - o0;
        const float4 q = ld4b(Pb + (size_t)v * DIM + l * 4);
        float m_h = -INFINITY, s_h = 0.f;
        float m_lm = -INFINITY, s_lm = 0.f, lsum = 0.f;
        for (int j = o0; j < o1; j++) {
            unsigned t = (unsigned)tt[j];
            int tail = t & 0xFFFFF;
            int r = t >> 20;
            const float4 k = ld4b(Pb + (size_t)tail * DIM + l * 4);
            const float4 ev = ld4b(eb + (size_t)tail * DIM + l * 4);
            const float4 rv = *(const float4*)(srel + r * DIM + l * 4);
            float part = q.x * k.x * rv.x + q.y * k.y * rv.y + q.z * k.z * rv.z + q.w * k.w * rv.w;
            part += __shfl_xor(part, 1);
            part += __shfl_xor(part, 2);
            part += __shfl_xor(part, 4);
            part *= sc;  // per-head logit (uniform within 8-lane half)
            float mn = fmaxf(m_h, part);
            float f = __expf(m_h - mn);
            float w = __expf(part - mn);
            s_h = s_h * f + w;
            ax = ax * f + w * ev.x * rv.x;
            ay = ay * f + w * ev.y * rv.y;
            az = az * f + w * ev.z * rv.z;
            aw = aw * f + w * ev.w * rv.w;
            m_h = mn;
            if (HOP0) {
                float other = __shfl_xor(part, 8);
                float lm = 0.5f * (part + other);  // uniform across 16 lanes
                float mn2 = fmaxf(m_lm, lm);
                s_lm = s_lm * __expf(m_lm - mn2) + __expf(lm - mn2);
                m_lm = mn2;
                lsum += lm;
                logit[j] = lm;
                if (l == 0 && tail < NITEMS) atomicAdd(&item_sum[tail], lm);
            }
        }
        float inv_sh = 1.0f / (s_h + 1e-16f);
        ax *= inv_sh;
        ay *= inv_sh;
        az *= inv_sh;
        aw *= inv_sh;
        if (HOP0) {
            if (l == 0 && v < NITEMS && deg > 0) atomicAdd(&item_sum[v], lsum);
            float inv_slm = 1.0f / (s_lm + 1e-16f);
            float degf = (float)deg;
            for (int j = o0 + l; j < o1; j += 16) {
                edge_score[eid[j]] = __expf(logit[j] - m_lm) * inv_slm * degf;
            }
        }
        // UI: users -> this entity
        int p0 = off[IBASE + v] - (EKG + EUI);
        int p1 = off[IBASE + v + 1] - (EKG + EUI);
        for (int j = p0; j < p1; j++) {
            int2 up = ipack[j];
            float w = __int_as_float(up.y);
            const float4 uv = ld4b(ub + (size_t)up.x * DIM + l * 4);
            ax += w * uv.x;
            ay += w * uv.y;
            az += w * uv.z;
            aw += w * uv.w;
        }
        float nsq = grp16_sum(ax * ax + ay * ay + az * az + aw * aw);
        float invn = 1.0f / fmaxf(sqrtf(nsq), 1e-12f);
        float ox = ax * invn, oy = ay * invn, oz = az * invn, ow = aw * invn;
        size_t base = (size_t)v * DIM + l * 4;
        if (HOP0) {
            st4b(enxtb + base, ox, oy, oz, ow);
        } else {
            const float4 b0 = *(const float4*)(ebase + base);
            const float4 p0v = ld4b(eprevb + base);
            float4 ro = {b0.x + p0v.x + ox, b0.y + p0v.y + oy, b0.z + p0v.z + oz,
                         b0.w + p0v.w + ow};
            *(float4*)(e_res + base) = ro;
        }
    } else {
        int u = v - NENT;
        int p0 = off[UBASE + u] - EKG;
        int p1 = off[UBASE + u + 1] - EKG;
        for (int j = p0; j < p1; j++) {
            int2 up = upack[j];
            float w = __int_as_float(up.y);
            const float4 ev = ld4b(eb + (size_t)up.x * DIM + l * 4);
            ax += w * ev.x;
            ay += w * ev.y;
            az += w * ev.z;
            aw += w * ev.w;
        }
        float nsq = grp16_sum(ax * ax + ay * ay + az * az + aw * aw);
        float invn = 1.0f / fmaxf(sqrtf(nsq), 1e-12f);
        float ox = ax * invn, oy = ay * invn, oz = az * invn, ow = aw * invn;
        size_t base = (size_t)u * DIM + l * 4;
        if (HOP0) {
            st4b(unxtb + base, ox, oy, oz, ow);
        } else {
            const float4 b0 = *(const float4*)(ubase + base);
            const float4 p0v = ld4b(uprevb + base);
            float4 ro = {b0.x + p0v.x + ox, b0.y + p0v.y + oy, b0.z + p0v.z + oz,
                         b0.w + p0v.w + ow};
            *(float4*)(u_res + base) = ro;
        }
    }
}

extern "C" void kernel_launch(void* const* d_in, const int* in_sizes, int n_in,
                              void* d_out, int out_size, void* d_ws, size_t ws_size,
                              hipStream_t stream) {
    const float* user_emb   = (const float*)d_in[0];
    const float* entity_emb = (const float*)d_in[1];
    const float* rel        = (const float*)d_in[2];
    const float* W_Q        = (const float*)d_in[3];
    const float* iwin       = (const float*)d_in[4];
    const int* ehead        = (const int*)d_in[5];
    const int* etail        = (const int*)d_in[6];
    const int* etype        = (const int*)d_in[7];
    const int* iuser        = (const int*)d_in[8];
    const int* iitem        = (const int*)d_in[9];

    float* out        = (float*)d_out;
    float* u_res      = out;
    float* e_res      = out + (size_t)NUSERS * DIM;
    float* edge_score = out + (size_t)(NUSERS + NENT) * DIM;
    float* item_sum   = edge_score + EKG;

    char* w = (char*)d_ws;
    auto alloc = [&](size_t bytes) -> void* {
        void* p = (void*)w;
        w += (bytes + 255) & ~(size_t)255;
        return p;
    };
    unsigned short* Pb  = (unsigned short*)alloc((size_t)NENT * DIM * 2);
    unsigned short* e0b = (unsigned short*)alloc((size_t)NENT * DIM * 2);
    unsigned short* eAb = (unsigned short*)alloc((size_t)NENT * DIM * 2);
    unsigned short* u0b = (unsigned short*)alloc((size_t)NUSERS * DIM * 2);
    unsigned short* uAb = (unsigned short*)alloc((size_t)NUSERS * DIM * 2);
    int* tt      = (int*)alloc((size_t)EKG * 4);
    int* eid     = (int*)alloc((size_t)EKG * 4);
    int2* upack  = (int2*)alloc((size_t)EUI * 8);
    int2* ipack  = (int2*)alloc((size_t)EUI * 8);
    int* rankK   = (int*)alloc((size_t)EKG * 4);
    int* rankU   = (int*)alloc((size_t)EUI * 4);
    int* rankI   = (int*)alloc((size_t)EUI * 4);
    float* logit = (float*)alloc((size_t)EKG * 4);
    int* cnt     = (int*)alloc((size_t)NTOT * 4);
    int* off     = (int*)alloc((size_t)(NTOT + 1) * 4);
    int* bsum    = (int*)alloc((size_t)SBLOCKS * 4);
    int* bpre    = (int*)alloc((size_t)SBLOCKS * 4);
    (void)ws_size; (void)in_sizes; (void)n_in; (void)out_size;

    hipMemsetAsync(cnt, 0, (size_t)NTOT * 4, stream);
    hipMemsetAsync(item_sum, 0, (size_t)NITEMS * 4, stream);

    // CSR build
    count_kernel<<<(EKG + 255) / 256, 256, 0, stream>>>(ehead, iuser, iitem, cnt, rankK, rankU,
                                                        rankI);
    scanA_kernel<<<SBLOCKS, 256, 0, stream>>>(cnt, bsum);
    scanB_kernel<<<1, 64, 0, stream>>>(bsum, bpre, off);
    scanC_kernel<<<SBLOCKS, 256, 0, stream>>>(cnt, bpre, off);

    const int KGG = (EKG + 255) / 256, UIG = (EUI + 255) / 256;
    for (int p = 0; p < 4; p++)
        fillKG_kernel<<<KGG, 256, 0, stream>>>(ehead, etail, etype, rankK, off, tt, eid,
                                               p * 20000, (p + 1) * 20000);
    for (int p = 0; p < 2; p++)
        fillUIu_kernel<<<UIG, 256, 0, stream>>>(iuser, iitem, iwin, rankU, off, upack,
                                                p * 20000, (p + 1) * 20000);
    for (int p = 0; p < 2; p++)
        fillUIi_kernel<<<UIG, 256, 0, stream>>>(iuser, iitem, iwin, rankI, off, ipack,
                                                p * 40000, (p + 1) * 40000);

    cvt_kernel<<<(NUSERS * DIM / 4 + 255) / 256, 256, 0, stream>>>(user_emb, u0b,
                                                                   NUSERS * DIM / 4);

    const int HOPG = (NENT + NUSERS) / 16;  // 7500 blocks

    // ---- hop 0 (includes Part A); writes bf16 next-tables only ----
    gemm_wq_kernel<0><<<NENT / 16, 256, 0, stream>>>(entity_emb, nullptr, W_Q, Pb, e0b);
    hop_kernel<true><<<HOPG, 256, 0, stream>>>(Pb, e0b, u0b, rel, off, tt, eid, upack, ipack,
                                               nullptr, nullptr, nullptr, nullptr, nullptr,
                                               nullptr, eAb, uAb, logit, edge_score, item_sum);

    // ---- hop 1; computes residuals res = base + prev + cur ----
    gemm_wq_kernel<1><<<NENT / 16, 256, 0, stream>>>(nullptr, eAb, W_Q, Pb, nullptr);
    hop_kernel<false><<<HOPG, 256, 0, stream>>>(Pb, eAb, uAb, rel, off, tt, eid, upack, ipack,
                                                entity_emb, user_emb, eAb, uAb, e_res, u_res,
                                                nullptr, nullptr, nullptr, nullptr, nullptr);
}

// Round 5
// 385.849 us; speedup vs baseline: 2.3375x; 1.0181x over previous
//
#include <hip/hip_runtime.h>
#include <math.h>

#define NUSERS 40000
#define NENT   80000
#define NITEMS 30000
#define DIM    64
#define EKG    800000
#define EUI    600000
#define NTOT   (NENT + NUSERS + NENT)   // 200000 combined count slots
#define UBASE  NENT                      // user counts start
#define IBASE  (NENT + NUSERS)           // item-side counts start

// ---------- bf16 helpers (RNE) ----------
struct __align__(8) us4 { unsigned short x, y, z, w; };
static __device__ __forceinline__ float b2f(unsigned short b) {
    return __uint_as_float(((unsigned)b) << 16);
}
static __device__ __forceinline__ unsigned short f2b(float f) {
    unsigned u = __float_as_uint(f);
    return (unsigned short)((u + 0x7FFFu + ((u >> 16) & 1u)) >> 16);
}
static __device__ __forceinline__ float4 ld4b(const unsigned short* p) {
    us4 v = *(const us4*)p;
    return make_float4(b2f(v.x), b2f(v.y), b2f(v.z), b2f(v.w));
}
static __device__ __forceinline__ void st4b(unsigned short* p, float a, float b, float c, float d) {
    us4 v = {f2b(a), f2b(b), f2b(c), f2b(d)};
    *(us4*)p = v;
}

static __device__ __forceinline__ float grp16_sum(float v) {
    v += __shfl_xor(v, 1);
    v += __shfl_xor(v, 2);
    v += __shfl_xor(v, 4);
    v += __shfl_xor(v, 8);
    return v;
}

// ---------- CSR build: count + packed (key|rank) streams + packed KG payload ----------
__global__ void count_kernel(const int* __restrict__ ehead, const int* __restrict__ etail,
                             const int* __restrict__ etype,
                             const int* __restrict__ iuser, const int* __restrict__ iitem,
                             int* __restrict__ cnt,
                             int* __restrict__ hrK, int* __restrict__ hrU, int* __restrict__ hrI,
                             int* __restrict__ tpack) {
    int e = blockIdx.x * blockDim.x + threadIdx.x;
    if (e < EKG) {
        int h = __builtin_nontemporal_load(&ehead[e]);
        int r = atomicAdd(&cnt[h], 1);
        hrK[e] = (h << 15) | r;   // h < 80000 (17b), rank < 32768
        tpack[e] = __builtin_nontemporal_load(&etail[e]) |
                   ((__builtin_nontemporal_load(&etype[e]) - 1) << 20);
    }
    if (e < EUI) {
        int u = __builtin_nontemporal_load(&iuser[e]);
        int r = atomicAdd(&cnt[UBASE + u], 1);
        hrU[e] = (u << 16) | r;   // u < 40000 (16b), rank < 65536
        int it = __builtin_nontemporal_load(&iitem[e]);
        int r2 = atomicAdd(&cnt[IBASE + it], 1);
        hrI[e] = (it << 15) | r2; // it < 80000 (17b), rank < 32768
    }
}

#define SCHUNK 2048
#define SBLOCKS ((NTOT + SCHUNK - 1) / SCHUNK)  // 98

__global__ void scanA_kernel(const int* __restrict__ cnt, int* __restrict__ bsum) {
    int b = blockIdx.x, tid = threadIdx.x;
    int base = b * SCHUNK + tid * 8;
    int ts = 0;
#pragma unroll
    for (int k = 0; k < 8; k++) {
        int i = base + k;
        ts += (i < NTOT) ? cnt[i] : 0;
    }
#pragma unroll
    for (int d = 1; d < 64; d <<= 1) ts += __shfl_xor(ts, d);
    __shared__ int ws[4];
    if ((tid & 63) == 0) ws[tid >> 6] = ts;
    __syncthreads();
    if (tid == 0) bsum[b] = ws[0] + ws[1] + ws[2] + ws[3];
}

__global__ void scanB_kernel(const int* __restrict__ bsum, int* __restrict__ bpre,
                             int* __restrict__ off) {
    int lane = threadIdx.x;
    int carry = 0;
    for (int base = 0; base < SBLOCKS; base += 64) {
        int i = base + lane;
        int x = (i < SBLOCKS) ? bsum[i] : 0;
        int inc = x;
#pragma unroll
        for (int d = 1; d < 64; d <<= 1) {
            int t = __shfl_up(inc, d);
            if (lane >= d) inc += t;
        }
        if (i < SBLOCKS) bpre[i] = carry + inc - x;
        carry += __shfl(inc, 63);
    }
    if (lane == 0) off[NTOT] = carry;
}

__global__ void scanC_kernel(const int* __restrict__ cnt, const int* __restrict__ bpre,
                             int* __restrict__ off) {
    __shared__ int wtot[4];
    int b = blockIdx.x, tid = threadIdx.x, lane = tid & 63, wid = tid >> 6;
    int base = b * SCHUNK + tid * 8;
    int vals[8];
    int ts = 0;
#pragma unroll
    for (int k = 0; k < 8; k++) {
        int i = base + k;
        int x = (i < NTOT) ? cnt[i] : 0;
        vals[k] = ts;
        ts += x;
    }
    int inc = ts;
#pragma unroll
    for (int d = 1; d < 64; d <<= 1) {
        int t = __shfl_up(inc, d);
        if (lane >= d) inc += t;
    }
    if (lane == 63) wtot[wid] = inc;
    __syncthreads();
    int wbase = 0;
    for (int w = 0; w < wid; w++) wbase += wtot[w];
    int tbase = bpre[b] + wbase + (inc - ts);
#pragma unroll
    for (int k = 0; k < 8; k++) {
        int i = base + k;
        if (i < NTOT) off[i] = tbase + vals[k];
    }
}

// ---- atomic-free range-partitioned fills (scatter slice stays L2-resident) ----
__global__ void fillKG_kernel(const int* __restrict__ hrK, const int* __restrict__ tpack,
                              const int* __restrict__ off,
                              int* __restrict__ tt, int* __restrict__ eid, int lo, int hi) {
    int e = blockIdx.x * blockDim.x + threadIdx.x;
    if (e >= EKG) return;
    int v = __builtin_nontemporal_load(&hrK[e]);
    int h = ((unsigned)v) >> 15;
    if (h < (unsigned)lo || h >= (unsigned)hi) return;
    int p = off[h] + (v & 0x7FFF);
    tt[p] = __builtin_nontemporal_load(&tpack[e]);
    eid[p] = e;
}

__global__ void fillUIu_kernel(const int* __restrict__ hrU, const int* __restrict__ iitem,
                               const float* __restrict__ iwin, const int* __restrict__ off,
                               int2* __restrict__ upack, int lo, int hi) {
    int e = blockIdx.x * blockDim.x + threadIdx.x;
    if (e >= EUI) return;
    int v = __builtin_nontemporal_load(&hrU[e]);
    int u = ((unsigned)v) >> 16;
    if (u < (unsigned)lo || u >= (unsigned)hi) return;
    int p = off[UBASE + u] - EKG + (v & 0xFFFF);
    upack[p] = make_int2(__builtin_nontemporal_load(&iitem[e]),
                         __float_as_int(__builtin_nontemporal_load(&iwin[e])));
}

__global__ void fillUIi_kernel(const int* __restrict__ hrI, const int* __restrict__ iuser,
                               const float* __restrict__ iwin, const int* __restrict__ off,
                               int2* __restrict__ ipack, int lo, int hi) {
    int e = blockIdx.x * blockDim.x + threadIdx.x;
    if (e >= EUI) return;
    int v = __builtin_nontemporal_load(&hrI[e]);
    int it = ((unsigned)v) >> 15;
    if (it < (unsigned)lo || it >= (unsigned)hi) return;
    int p = off[IBASE + it] - (EKG + EUI) + (v & 0x7FFF);
    ipack[p] = make_int2(__builtin_nontemporal_load(&iuser[e]),
                         __float_as_int(__builtin_nontemporal_load(&iwin[e])));
}

// ---------- f32 -> bf16 table convert ----------
__global__ void cvt_kernel(const float* __restrict__ in, unsigned short* __restrict__ out,
                           int n4) {
    int i = blockIdx.x * blockDim.x + threadIdx.x;
    if (i >= n4) return;
    float4 v = *(const float4*)(in + (size_t)i * 4);
    st4b(out + (size_t)i * 4, v.x, v.y, v.z, v.w);
}

// ---------- P = X @ W_Q  (bf16 out; MODE 0: f32 in + also emit bf16 copy of X) ----------
template <int MODE>
__global__ void gemm_wq_kernel(const float* __restrict__ Xf,
                               const unsigned short* __restrict__ Xb_in,
                               const float* __restrict__ W,
                               unsigned short* __restrict__ Pb,
                               unsigned short* __restrict__ Xb_out) {
    __shared__ float Wl[64 * 64];
    int tid = threadIdx.x;
    for (int i = tid; i < 64 * 64; i += 256) Wl[i] = W[i];
    __syncthreads();
    int rloc = tid >> 4;
    int c4 = (tid & 15) * 4;
    int row = blockIdx.x * 16 + rloc;
    float ax = 0, ay = 0, az = 0, aw = 0;
#pragma unroll 8
    for (int d = 0; d < 64; d++) {
        float xv = (MODE == 0) ? Xf[(size_t)row * DIM + d] : b2f(Xb_in[(size_t)row * DIM + d]);
        const float4 w = *(const float4*)&Wl[d * 64 + c4];
        ax += xv * w.x;
        ay += xv * w.y;
        az += xv * w.z;
        aw += xv * w.w;
    }
    st4b(Pb + (size_t)row * DIM + c4, ax, ay, az, aw);
    if (MODE == 0) {
        const float4 xx = *(const float4*)(Xf + (size_t)row * DIM + c4);
        st4b(Xb_out + (size_t)row * DIM + c4, xx.x, xx.y, xx.z, xx.w);
    }
}

// ---------- fused hop: single-pass attn+softmax+aggregate+norm (+residual on hop1) ----------
// Logits are bounded (|x| << 1 by input construction: 0.1-scale or l2-normed embeddings),
// so softmax uses exp(x) directly with no max subtraction (mathematically identical).
template <bool HOP0>
__global__ void hop_kernel(const unsigned short* __restrict__ Pb,
                           const unsigned short* __restrict__ eb,
                           const unsigned short* __restrict__ ub,
                           const float* __restrict__ rel,
                           const int* __restrict__ off,
                           const int* __restrict__ tt, const int* __restrict__ eid,
                           const int2* __restrict__ upack, const int2* __restrict__ ipack,
                           const float* __restrict__ ebase, const float* __restrict__ ubase,
                           const unsigned short* __restrict__ eprevb,
                           const unsigned short* __restrict__ uprevb,
                           float* __restrict__ e_res, float* __restrict__ u_res,
                           unsigned short* __restrict__ enxtb, unsigned short* __restrict__ unxtb,
                           float* __restrict__ logit, float* __restrict__ edge_score,
                           float* __restrict__ item_sum) {
    __shared__ float srel[7 * DIM];
    int tid = threadIdx.x;
    for (int i = tid; i < 7 * DIM; i += 256) srel[i] = rel[i];
    __syncthreads();
    int g = tid >> 4, l = tid & 15;
    int v = blockIdx.x * 16 + g;
    const float sc = 0.17677669529663687f;  // 1/sqrt(32)
    float ax = 0, ay = 0, az = 0, aw = 0;

    if (v < NENT) {
        int o0 = off[v], o1 = off[v + 1];
        int deg = o1 - o0;
        const float4 q = ld4b(Pb + (size_t)v * DIM + l * 4);
        float s_h = 0.f;
        float s_lm = 0.f, lsum = 0.f;
        for (int j = o0; j < o1; j++) {
            unsigned t = (unsigned)tt[j];
            int tail = t & 0xFFFFF;
            int r = t >> 20;
            const float4 k = ld4b(Pb + (size_t)tail * DIM + l * 4);
            const float4 ev = ld4b(eb + (size_t)tail * DIM + l * 4);
            const float4 rv = *(const float4*)(srel + r * DIM + l * 4);
            float part = q.x * k.x * rv.x + q.y * k.y * rv.y + q.z * k.z * rv.z + q.w * k.w * rv.w;
            part += __shfl_xor(part, 1);
            part += __shfl_xor(part, 2);
            part += __shfl_xor(part, 4);
            part *= sc;  // per-head logit (uniform within 8-lane half)
            float w = __expf(part);
            s_h += w;
            ax += w * ev.x * rv.x;
            ay += w * ev.y * rv.y;
            az += w * ev.z * rv.z;
            aw += w * ev.w * rv.w;
            if (HOP0) {
                float other = __shfl_xor(part, 8);
                float lm = 0.5f * (part + other);  // uniform across 16 lanes
                s_lm += __expf(lm);
                lsum += lm;
                if (l == 0) {
                    logit[j] = lm;
                    if (tail < NITEMS) atomicAdd(&item_sum[tail], lm);
                }
            }
        }
        float inv_sh = 1.0f / (s_h + 1e-16f);
        ax *= inv_sh;
        ay *= inv_sh;
        az *= inv_sh;
        aw *= inv_sh;
        if (HOP0) {
            if (l == 0 && v < NITEMS && deg > 0) atomicAdd(&item_sum[v], lsum);
            float inv_slm = 1.0f / (s_lm + 1e-16f);
            float degf = (float)deg;
            for (int j = o0 + l; j < o1; j += 16) {
                edge_score[eid[j]] = __expf(logit[j]) * inv_slm * degf;
            }
        }
        // UI: users -> this entity
        int p0 = off[IBASE + v] - (EKG + EUI);
        int p1 = off[IBASE + v + 1] - (EKG + EUI);
        for (int j = p0; j < p1; j++) {
            int2 up = ipack[j];
            float w = __int_as_float(up.y);
            const float4 uv = ld4b(ub + (size_t)up.x * DIM + l * 4);
            ax += w * uv.x;
            ay += w * uv.y;
            az += w * uv.z;
            aw += w * uv.w;
        }
        float nsq = grp16_sum(ax * ax + ay * ay + az * az + aw * aw);
        float invn = 1.0f / fmaxf(sqrtf(nsq), 1e-12f);
        float ox = ax * invn, oy = ay * invn, oz = az * invn, ow = aw * invn;
        size_t base = (size_t)v * DIM + l * 4;
        if (HOP0) {
            st4b(enxtb + base, ox, oy, oz, ow);
        } else {
            const float4 b0 = *(const float4*)(ebase + base);
            const float4 p0v = ld4b(eprevb + base);
            float4 ro = {b0.x + p0v.x + ox, b0.y + p0v.y + oy, b0.z + p0v.z + oz,
                         b0.w + p0v.w + ow};
            *(float4*)(e_res + base) = ro;
        }
    } else {
        int u = v - NENT;
        int p0 = off[UBASE + u] - EKG;
        int p1 = off[UBASE + u + 1] - EKG;
        for (int j = p0; j < p1; j++) {
            int2 up = upack[j];
            float w = __int_as_float(up.y);
            const float4 ev = ld4b(eb + (size_t)up.x * DIM + l * 4);
            ax += w * ev.x;
            ay += w * ev.y;
            az += w * ev.z;
            aw += w * ev.w;
        }
        float nsq = grp16_sum(ax * ax + ay * ay + az * az + aw * aw);
        float invn = 1.0f / fmaxf(sqrtf(nsq), 1e-12f);
        float ox = ax * invn, oy = ay * invn, oz = az * invn, ow = aw * invn;
        size_t base = (size_t)u * DIM + l * 4;
        if (HOP0) {
            st4b(unxtb + base, ox, oy, oz, ow);
        } else {
            const float4 b0 = *(const float4*)(ubase + base);
            const float4 p0v = ld4b(uprevb + base);
            float4 ro = {b0.x + p0v.x + ox, b0.y + p0v.y + oy, b0.z + p0v.z + oz,
                         b0.w + p0v.w + ow};
            *(float4*)(u_res + base) = ro;
        }
    }
}

extern "C" void kernel_launch(void* const* d_in, const int* in_sizes, int n_in,
                              void* d_out, int out_size, void* d_ws, size_t ws_size,
                              hipStream_t stream) {
    const float* user_emb   = (const float*)d_in[0];
    const float* entity_emb = (const float*)d_in[1];
    const float* rel        = (const float*)d_in[2];
    const float* W_Q        = (const float*)d_in[3];
    const float* iwin       = (const float*)d_in[4];
    const int* ehead        = (const int*)d_in[5];
    const int* etail        = (const int*)d_in[6];
    const int* etype        = (const int*)d_in[7];
    const int* iuser        = (const int*)d_in[8];
    const int* iitem        = (const int*)d_in[9];

    float* out        = (float*)d_out;
    float* u_res      = out;
    float* e_res      = out + (size_t)NUSERS * DIM;
    float* edge_score = out + (size_t)(NUSERS + NENT) * DIM;
    float* item_sum   = edge_score + EKG;

    char* w = (char*)d_ws;
    auto alloc = [&](size_t bytes) -> void* {
        void* p = (void*)w;
        w += (bytes + 255) & ~(size_t)255;
        return p;
    };
    unsigned short* Pb  = (unsigned short*)alloc((size_t)NENT * DIM * 2);
    unsigned short* e0b = (unsigned short*)alloc((size_t)NENT * DIM * 2);
    unsigned short* eAb = (unsigned short*)alloc((size_t)NENT * DIM * 2);
    unsigned short* u0b = (unsigned short*)alloc((size_t)NUSERS * DIM * 2);
    unsigned short* uAb = (unsigned short*)alloc((size_t)NUSERS * DIM * 2);
    int* tt      = (int*)alloc((size_t)EKG * 4);
    int* eid     = (int*)alloc((size_t)EKG * 4);
    int2* upack  = (int2*)alloc((size_t)EUI * 8);
    int2* ipack  = (int2*)alloc((size_t)EUI * 8);
    int* hrK     = (int*)alloc((size_t)EKG * 4);
    int* hrU     = (int*)alloc((size_t)EUI * 4);
    int* hrI     = (int*)alloc((size_t)EUI * 4);
    int* tpack   = (int*)alloc((size_t)EKG * 4);
    float* logit = (float*)alloc((size_t)EKG * 4);
    int* cnt     = (int*)alloc((size_t)NTOT * 4);
    int* off     = (int*)alloc((size_t)(NTOT + 1) * 4);
    int* bsum    = (int*)alloc((size_t)SBLOCKS * 4);
    int* bpre    = (int*)alloc((size_t)SBLOCKS * 4);
    (void)ws_size; (void)in_sizes; (void)n_in; (void)out_size;

    hipMemsetAsync(cnt, 0, (size_t)NTOT * 4, stream);
    hipMemsetAsync(item_sum, 0, (size_t)NITEMS * 4, stream);

    // CSR build
    count_kernel<<<(EKG + 255) / 256, 256, 0, stream>>>(ehead, etail, etype, iuser, iitem, cnt,
                                                        hrK, hrU, hrI, tpack);
    scanA_kernel<<<SBLOCKS, 256, 0, stream>>>(cnt, bsum);
    scanB_kernel<<<1, 64, 0, stream>>>(bsum, bpre, off);
    scanC_kernel<<<SBLOCKS, 256, 0, stream>>>(cnt, bpre, off);

    const int KGG = (EKG + 255) / 256, UIG = (EUI + 255) / 256;
    for (int p = 0; p < 2; p++)
        fillKG_kernel<<<KGG, 256, 0, stream>>>(hrK, tpack, off, tt, eid,
                                               p * 40000, (p + 1) * 40000);
    for (int p = 0; p < 2; p++)
        fillUIu_kernel<<<UIG, 256, 0, stream>>>(hrU, iitem, iwin, off, upack,
                                                p * 20000, (p + 1) * 20000);
    for (int p = 0; p < 2; p++)
        fillUIi_kernel<<<UIG, 256, 0, stream>>>(hrI, iuser, iwin, off, ipack,
                                                p * 40000, (p + 1) * 40000);

    cvt_kernel<<<(NUSERS * DIM / 4 + 255) / 256, 256, 0, stream>>>(user_emb, u0b,
                                                                   NUSERS * DIM / 4);

    const int HOPG = (NENT + NUSERS) / 16;  // 7500 blocks

    // ---- hop 0 (includes Part A); writes bf16 next-tables only ----
    gemm_wq_kernel<0><<<NENT / 16, 256, 0, stream>>>(entity_emb, nullptr, W_Q, Pb, e0b);
    hop_kernel<true><<<HOPG, 256, 0, stream>>>(Pb, e0b, u0b, rel, off, tt, eid, upack, ipack,
                                               nullptr, nullptr, nullptr, nullptr, nullptr,
                                               nullptr, eAb, uAb, logit, edge_score, item_sum);

    // ---- hop 1; computes residuals res = base + prev + cur ----
    gemm_wq_kernel<1><<<NENT / 16, 256, 0, stream>>>(nullptr, eAb, W_Q, Pb, nullptr);
    hop_kernel<false><<<HOPG, 256, 0, stream>>>(Pb, eAb, uAb, rel, off, tt, eid, upack, ipack,
                                                entity_emb, user_emb, eAb, uAb, e_res, u_res,
                                                nullptr, nullptr, nullptr, nullptr, nullptr);
}